// Round 1
// baseline (393.888 us; speedup 1.0000x reference)
//
#include <hip/hip_runtime.h>

#define S_LEN 4096
#define NHEAD 16
#define DHEAD 64
#define HID 1024

typedef float f32x4 __attribute__((ext_vector_type(4)));
typedef unsigned short u16x8 __attribute__((ext_vector_type(8)));
typedef __bf16 bf16x8 __attribute__((ext_vector_type(8)));

__device__ __forceinline__ unsigned short f2bf(float f) {
  union { float f; unsigned u; } x; x.f = f;
  return (unsigned short)((x.u + 0x7FFFu + ((x.u >> 16) & 1u)) >> 16);
}
__device__ __forceinline__ float bf2f(unsigned short u) {
  union { unsigned u; float f; } x; x.u = ((unsigned)u) << 16;
  return x.f;
}
__device__ __forceinline__ f32x4 mfma16(u16x8 a, u16x8 b, f32x4 c) {
  return __builtin_amdgcn_mfma_f32_16x16x32_bf16(
      __builtin_bit_cast(bf16x8, a), __builtin_bit_cast(bf16x8, b), c, 0, 0, 0);
}
__device__ __forceinline__ void gload16(const void* g, void* l) {
  __builtin_amdgcn_global_load_lds(
      (const __attribute__((address_space(1))) void*)g,
      (__attribute__((address_space(3))) void*)l, 16, 0, 0);
}

// ---------- fp32 -> bf16 convert, 4 elems/thread ----------
__global__ void k_cvt(const float4* __restrict__ in, ushort4* __restrict__ out, int n4) {
  int i = blockIdx.x * blockDim.x + threadIdx.x;
  if (i >= n4) return;
  float4 v = in[i];
  ushort4 o;
  o.x = f2bf(v.x); o.y = f2bf(v.y); o.z = f2bf(v.z); o.w = f2bf(v.w);
  out[i] = o;
}

// ---------- rope table: tab[s*32+i] = (cos, sin) of s * 10000^(-i/32) ----------
__global__ void k_rope_tab(float2* __restrict__ tab) {
  int idx = blockIdx.x * blockDim.x + threadIdx.x;
  int s = idx >> 5, i = idx & 31;
  float inv = __powf(10000.0f, -(float)i * (1.0f / 32.0f));
  float ang = (float)s * inv;
  float sn, cs;
  sincosf(ang, &sn, &cs);
  tab[idx] = make_float2(cs, sn);
}

// ---------- rope + split: qkv[S][3072] bf16 -> Q,K [H][S][64] bf16 ----------
__global__ void k_rope_split(const unsigned short* __restrict__ qkv,
                             const float2* __restrict__ tab,
                             unsigned short* __restrict__ Q,
                             unsigned short* __restrict__ Ko) {
  int s = blockIdx.x;
  int t = threadIdx.x;  // 512 threads
  int h = t >> 5, i = t & 31;
  const unsigned short* row = qkv + (size_t)s * 3072;
  float2 cs = tab[s * 32 + i];
  float q1 = bf2f(row[h * 64 + i]);
  float q2 = bf2f(row[h * 64 + i + 32]);
  float k1 = bf2f(row[1024 + h * 64 + i]);
  float k2 = bf2f(row[1024 + h * 64 + i + 32]);
  size_t o = ((size_t)h * S_LEN + s) * 64 + i;
  Q[o]      = f2bf(q1 * cs.x - q2 * cs.y);
  Q[o + 32] = f2bf(q2 * cs.x + q1 * cs.y);
  Ko[o]      = f2bf(k1 * cs.x - k2 * cs.y);
  Ko[o + 32] = f2bf(k2 * cs.x + k1 * cs.y);
}

// ---------- V transpose: qkv v-part [S][h*64+d] -> Vt [H][64][S] ----------
__global__ void k_vt(const unsigned short* __restrict__ qkv,
                     unsigned short* __restrict__ Vt) {
  __shared__ unsigned short tile[64][65];
  int st = blockIdx.x, h = blockIdx.y;
  int t = threadIdx.x;  // 256
  int r = t >> 2, c0 = (t & 3) * 16;
  const unsigned short* src = qkv + (size_t)(st * 64 + r) * 3072 + 2048 + h * 64 + c0;
  u16x8 a = *(const u16x8*)src;
  u16x8 b = *(const u16x8*)(src + 8);
#pragma unroll
  for (int j = 0; j < 8; ++j) { tile[r][c0 + j] = a[j]; tile[r][c0 + 8 + j] = b[j]; }
  __syncthreads();
  unsigned short* dst = Vt + ((size_t)h * 64 + r) * S_LEN + st * 64 + c0;
  u16x8 o0, o1;
#pragma unroll
  for (int j = 0; j < 8; ++j) { o0[j] = tile[c0 + j][r]; o1[j] = tile[c0 + 8 + j][r]; }
  *(u16x8*)dst = o0;
  *(u16x8*)(dst + 8) = o1;
}

// ---------- GEMM: C[M][N] = A[M][K] * B[N][K]^T  (all bf16 in, OutT out) ----------
__device__ __forceinline__ void stc(float* p, float v) { *p = v; }
__device__ __forceinline__ void stc(unsigned short* p, float v) { *p = f2bf(v); }

template <typename OutT>
__global__ __launch_bounds__(256) void gemm_bt(
    const unsigned short* __restrict__ A, const unsigned short* __restrict__ B,
    OutT* __restrict__ C, int M, int N, int K) {
  __shared__ __attribute__((aligned(16))) unsigned short As[2][128][64];
  __shared__ __attribute__((aligned(16))) unsigned short Bs[2][128][64];
  const int tid = threadIdx.x;
  const int w = tid >> 6, lane = tid & 63;
  const int bm = blockIdx.y * 128, bn = blockIdx.x * 128;
  const int wr = w >> 1, wc = w & 1;
  const int l8 = lane >> 3;
  const int c8 = (lane & 7) * 8;
  f32x4 acc[4][4] = {};

  auto stage = [&](int buf, int k0) {
#pragma unroll
    for (int c = 0; c < 4; ++c) {
      int row = w * 32 + c * 8;
      gload16(A + (size_t)(bm + row + l8) * K + k0 + c8, &As[buf][row][0]);
      gload16(B + (size_t)(bn + row + l8) * K + k0 + c8, &Bs[buf][row][0]);
    }
  };

  const int nk = K >> 6;
  stage(0, 0);
  int cur = 0;
  for (int kt = 0; kt < nk; ++kt) {
    __syncthreads();
    if (kt + 1 < nk) stage(cur ^ 1, (kt + 1) << 6);
#pragma unroll
    for (int kk = 0; kk < 2; ++kk) {
      u16x8 af[4], bfr[4];
#pragma unroll
      for (int m = 0; m < 4; ++m)
        af[m] = *(const u16x8*)&As[cur][wr * 64 + m * 16 + (lane & 15)][kk * 32 + (lane >> 4) * 8];
#pragma unroll
      for (int n = 0; n < 4; ++n)
        bfr[n] = *(const u16x8*)&Bs[cur][wc * 64 + n * 16 + (lane & 15)][kk * 32 + (lane >> 4) * 8];
#pragma unroll
      for (int m = 0; m < 4; ++m)
#pragma unroll
        for (int n = 0; n < 4; ++n)
          acc[m][n] = mfma16(af[m], bfr[n], acc[m][n]);
    }
    cur ^= 1;
  }
#pragma unroll
  for (int m = 0; m < 4; ++m) {
    int row = bm + wr * 64 + m * 16 + (lane >> 4) * 4;
#pragma unroll
    for (int n = 0; n < 4; ++n) {
      int col = bn + wc * 64 + n * 16 + (lane & 15);
#pragma unroll
      for (int j = 0; j < 4; ++j) stc(&C[(size_t)(row + j) * N + col], acc[m][n][j]);
    }
  }
}

// ---------- flash attention (causal), block = (64 q-rows, 1 head), 4 waves ----------
__global__ __launch_bounds__(256) void flash_attn(
    const unsigned short* __restrict__ Q,
    const unsigned short* __restrict__ Kt,
    const unsigned short* __restrict__ Vt,
    unsigned short* __restrict__ O) {
  __shared__ __attribute__((aligned(16))) unsigned short Ks[64][64];
  __shared__ __attribute__((aligned(16))) unsigned short Vs[64][64];  // Vs[d][kv]
  __shared__ __attribute__((aligned(16))) unsigned short Ps[4][16][64];
  const int tid = threadIdx.x;
  const int w = tid >> 6, lane = tid & 63;
  const int h = blockIdx.y;
  const int qt = (gridDim.x - 1) - blockIdx.x;  // heavy blocks first
  const float scale = 0.125f;

  const int qrow = qt * 64 + w * 16 + (lane & 15);
  const unsigned short* qp = Q + ((size_t)h * S_LEN + qrow) * 64 + (lane >> 4) * 8;
  const u16x8 q0 = *(const u16x8*)qp;
  const u16x8 q1 = *(const u16x8*)(qp + 32);

  f32x4 acc[4] = {};
  float m_run[4] = {-1e30f, -1e30f, -1e30f, -1e30f};
  float l_run[4] = {0.f, 0.f, 0.f, 0.f};
  const int r0 = (lane >> 4) * 4;

  for (int kvt = 0; kvt <= qt; ++kvt) {
    __syncthreads();  // prior tile's reads done before overwrite
    {
      const unsigned short* kbase = Kt + ((size_t)h * S_LEN + kvt * 64) * 64;
#pragma unroll
      for (int c = 0; c < 2; ++c) {
        int off = (w * 2 + c) * 512;  // elements
        gload16(kbase + off + lane * 8, (char*)&Ks[0][0] + (size_t)off * 2);
      }
#pragma unroll
      for (int c = 0; c < 2; ++c) {
        int d0 = w * 16 + c * 8;
        gload16(Vt + ((size_t)h * 64 + d0 + (lane >> 3)) * S_LEN + kvt * 64 + (lane & 7) * 8,
                &Vs[d0][0]);
      }
    }
    __syncthreads();

    // scores: wave's 16 q rows x 64 kv
    f32x4 sc[4] = {};
#pragma unroll
    for (int kk = 0; kk < 2; ++kk) {
      u16x8 aq = kk ? q1 : q0;
#pragma unroll
      for (int nf = 0; nf < 4; ++nf) {
        u16x8 bk = *(const u16x8*)&Ks[nf * 16 + (lane & 15)][kk * 32 + (lane >> 4) * 8];
        sc[nf] = mfma16(aq, bk, sc[nf]);
      }
    }
    const bool diag = (kvt == qt);
#pragma unroll
    for (int j = 0; j < 4; ++j) {
      const int qg = qt * 64 + w * 16 + r0 + j;
      float mx = -1e30f;
#pragma unroll
      for (int nf = 0; nf < 4; ++nf) {
        float v = sc[nf][j] * scale;
        if (diag) {
          int kg = kvt * 64 + nf * 16 + (lane & 15);
          if (kg > qg) v = -1e30f;
        }
        sc[nf][j] = v;
        mx = fmaxf(mx, v);
      }
#pragma unroll
      for (int msk = 1; msk < 16; msk <<= 1) mx = fmaxf(mx, __shfl_xor(mx, msk, 64));
      float mnew = fmaxf(m_run[j], mx);
      float alpha = __expf(m_run[j] - mnew);
      float rsum = 0.f;
#pragma unroll
      for (int nf = 0; nf < 4; ++nf) {
        float p = __expf(sc[nf][j] - mnew);
        rsum += p;
        Ps[w][r0 + j][nf * 16 + (lane & 15)] = f2bf(p);
      }
#pragma unroll
      for (int msk = 1; msk < 16; msk <<= 1) rsum += __shfl_xor(rsum, msk, 64);
      l_run[j] = l_run[j] * alpha + rsum;
      m_run[j] = mnew;
#pragma unroll
      for (int df = 0; df < 4; ++df) acc[df][j] *= alpha;
    }
    // wave-level fence: Ps writes (cross-lane, same wave) visible before reads
    asm volatile("s_waitcnt lgkmcnt(0)" ::: "memory");
#pragma unroll
    for (int kk = 0; kk < 2; ++kk) {
      u16x8 ap = *(const u16x8*)&Ps[w][lane & 15][kk * 32 + (lane >> 4) * 8];
#pragma unroll
      for (int df = 0; df < 4; ++df) {
        u16x8 bv = *(const u16x8*)&Vs[df * 16 + (lane & 15)][kk * 32 + (lane >> 4) * 8];
        acc[df] = mfma16(ap, bv, acc[df]);
      }
    }
  }
#pragma unroll
  for (int j = 0; j < 4; ++j) {
    const int qg = qt * 64 + w * 16 + r0 + j;
    float inv = 1.0f / l_run[j];
#pragma unroll
    for (int df = 0; df < 4; ++df)
      O[(size_t)qg * HID + h * 64 + df * 16 + (lane & 15)] = f2bf(acc[df][j] * inv);
  }
}

extern "C" void kernel_launch(void* const* d_in, const int* in_sizes, int n_in,
                              void* d_out, int out_size, void* d_ws, size_t ws_size,
                              hipStream_t stream) {
  const float* x = (const float*)d_in[0];       // [4096][1024]
  const float* w_qkv = (const float*)d_in[1];   // [3072][1024]
  const float* w_out = (const float*)d_in[2];   // [1024][1024]
  float* out = (float*)d_out;                   // [4096][1024] f32
  char* ws = (char*)d_ws;

  unsigned short* xb    = (unsigned short*)(ws + 0);          // 8 MB
  unsigned short* wqkvb = (unsigned short*)(ws + 8388608);    // 6 MB
  unsigned short* woutb = (unsigned short*)(ws + 14680064);   // 2 MB
  unsigned short* qkvb  = (unsigned short*)(ws + 16777216);   // 24 MB [S][3072]
  unsigned short* Qb    = (unsigned short*)(ws + 41943040);   // 8 MB [H][S][64]
  unsigned short* Kb    = (unsigned short*)(ws + 50331648);   // 8 MB
  unsigned short* Vtb   = (unsigned short*)(ws + 58720256);   // 8 MB [H][64][S]
  unsigned short* attnb = (unsigned short*)(ws + 67108864);   // 8 MB [S][1024]
  float2* tab           = (float2*)(ws + 75497472);           // 1 MB

  // converts
  k_cvt<<<dim3(4096), dim3(256), 0, stream>>>((const float4*)x, (ushort4*)xb, 1048576);
  k_cvt<<<dim3(3072), dim3(256), 0, stream>>>((const float4*)w_qkv, (ushort4*)wqkvb, 786432);
  k_cvt<<<dim3(1024), dim3(256), 0, stream>>>((const float4*)w_out, (ushort4*)woutb, 262144);
  k_rope_tab<<<dim3(512), dim3(256), 0, stream>>>(tab);

  // QKV projection: [4096][3072] = xb [4096][1024] @ wqkvb[3072][1024]^T
  gemm_bt<unsigned short><<<dim3(24, 32), dim3(256), 0, stream>>>(xb, wqkvb, qkvb, 4096, 3072, 1024);

  // rope + layout split
  k_rope_split<<<dim3(4096), dim3(512), 0, stream>>>(qkvb, tab, Qb, Kb);
  k_vt<<<dim3(64, 16), dim3(256), 0, stream>>>(qkvb, Vtb);

  // flash attention
  flash_attn<<<dim3(64, 16), dim3(256), 0, stream>>>(Qb, Kb, Vtb, attnb);

  // output projection: [4096][1024] = attnb @ woutb^T
  gemm_bt<float><<<dim3(8, 32), dim3(256), 0, stream>>>(attnb, woutb, out, 4096, 1024, 1024);
}

// Round 2
// 300.916 us; speedup vs baseline: 1.3090x; 1.3090x over previous
//
#include <hip/hip_runtime.h>

#define S_LEN 4096
#define NHEAD 16
#define DHEAD 64
#define HID 1024

typedef float f32x4 __attribute__((ext_vector_type(4)));
typedef unsigned short u16x8 __attribute__((ext_vector_type(8)));
typedef __bf16 bf16x8 __attribute__((ext_vector_type(8)));

__device__ __forceinline__ unsigned short f2bf(float f) {
  union { float f; unsigned u; } x; x.f = f;
  return (unsigned short)((x.u + 0x7FFFu + ((x.u >> 16) & 1u)) >> 16);
}
__device__ __forceinline__ float bf2f(unsigned short u) {
  union { unsigned u; float f; } x; x.u = ((unsigned)u) << 16;
  return x.f;
}
__device__ __forceinline__ f32x4 mfma16(u16x8 a, u16x8 b, f32x4 c) {
  return __builtin_amdgcn_mfma_f32_16x16x32_bf16(
      __builtin_bit_cast(bf16x8, a), __builtin_bit_cast(bf16x8, b), c, 0, 0, 0);
}
__device__ __forceinline__ void gload16(const void* g, void* l) {
  __builtin_amdgcn_global_load_lds(
      (const __attribute__((address_space(1))) void*)g,
      (__attribute__((address_space(3))) void*)l, 16, 0, 0);
}

// ---------- fp32 -> bf16 convert, 4 elems/thread ----------
__global__ void k_cvt(const float4* __restrict__ in, ushort4* __restrict__ out, int n4) {
  int i = blockIdx.x * blockDim.x + threadIdx.x;
  if (i >= n4) return;
  float4 v = in[i];
  ushort4 o;
  o.x = f2bf(v.x); o.y = f2bf(v.y); o.z = f2bf(v.z); o.w = f2bf(v.w);
  out[i] = o;
}

// ---------- rope table ----------
__global__ void k_rope_tab(float2* __restrict__ tab) {
  int idx = blockIdx.x * blockDim.x + threadIdx.x;
  int s = idx >> 5, i = idx & 31;
  float inv = __powf(10000.0f, -(float)i * (1.0f / 32.0f));
  float ang = (float)s * inv;
  float sn, cs;
  sincosf(ang, &sn, &cs);
  tab[idx] = make_float2(cs, sn);
}

// ---------- rope + split: qkv[S][3072] bf16 -> Q,K [H][S][64]; K pre-scaled by 1/8 ----------
__global__ void k_rope_split(const unsigned short* __restrict__ qkv,
                             const float2* __restrict__ tab,
                             unsigned short* __restrict__ Q,
                             unsigned short* __restrict__ Ko) {
  int s = blockIdx.x;
  int t = threadIdx.x;  // 512 threads
  int h = t >> 5, i = t & 31;
  const unsigned short* row = qkv + (size_t)s * 3072;
  float2 cs = tab[s * 32 + i];
  float q1 = bf2f(row[h * 64 + i]);
  float q2 = bf2f(row[h * 64 + i + 32]);
  float k1 = bf2f(row[1024 + h * 64 + i]);
  float k2 = bf2f(row[1024 + h * 64 + i + 32]);
  size_t o = ((size_t)h * S_LEN + s) * 64 + i;
  Q[o]      = f2bf(q1 * cs.x - q2 * cs.y);
  Q[o + 32] = f2bf(q2 * cs.x + q1 * cs.y);
  Ko[o]      = f2bf((k1 * cs.x - k2 * cs.y) * 0.125f);
  Ko[o + 32] = f2bf((k2 * cs.x + k1 * cs.y) * 0.125f);
}

// ---------- V transpose: qkv v-part [S][h*64+d] -> Vt [H][64][S] ----------
__global__ void k_vt(const unsigned short* __restrict__ qkv,
                     unsigned short* __restrict__ Vt) {
  __shared__ unsigned short tile[64][65];
  int st = blockIdx.x, h = blockIdx.y;
  int t = threadIdx.x;  // 256
  int r = t >> 2, c0 = (t & 3) * 16;
  const unsigned short* src = qkv + (size_t)(st * 64 + r) * 3072 + 2048 + h * 64 + c0;
  u16x8 a = *(const u16x8*)src;
  u16x8 b = *(const u16x8*)(src + 8);
#pragma unroll
  for (int j = 0; j < 8; ++j) { tile[r][c0 + j] = a[j]; tile[r][c0 + 8 + j] = b[j]; }
  __syncthreads();
  unsigned short* dst = Vt + ((size_t)h * 64 + r) * S_LEN + st * 64 + c0;
  u16x8 o0, o1;
#pragma unroll
  for (int j = 0; j < 8; ++j) { o0[j] = tile[c0 + j][r]; o1[j] = tile[c0 + 8 + j][r]; }
  *(u16x8*)dst = o0;
  *(u16x8*)(dst + 8) = o1;
}

// ---------- GEMM: C[M][N] = A[M][K] * B[N][K]^T ----------
__device__ __forceinline__ void stc(float* p, float v) { *p = v; }
__device__ __forceinline__ void stc(unsigned short* p, float v) { *p = f2bf(v); }

template <typename OutT>
__global__ __launch_bounds__(256) void gemm_bt(
    const unsigned short* __restrict__ A, const unsigned short* __restrict__ B,
    OutT* __restrict__ C, int M, int N, int K) {
  __shared__ __attribute__((aligned(16))) unsigned short As[2][128][64];
  __shared__ __attribute__((aligned(16))) unsigned short Bs[2][128][64];
  const int tid = threadIdx.x;
  const int w = tid >> 6, lane = tid & 63;
  const int bm = blockIdx.y * 128, bn = blockIdx.x * 128;
  const int wr = w >> 1, wc = w & 1;
  const int l8 = lane >> 3;
  const int c8 = (lane & 7) * 8;
  f32x4 acc[4][4] = {};

  auto stage = [&](int buf, int k0) {
#pragma unroll
    for (int c = 0; c < 4; ++c) {
      int row = w * 32 + c * 8;
      gload16(A + (size_t)(bm + row + l8) * K + k0 + c8, &As[buf][row][0]);
      gload16(B + (size_t)(bn + row + l8) * K + k0 + c8, &Bs[buf][row][0]);
    }
  };

  const int nk = K >> 6;
  stage(0, 0);
  int cur = 0;
  for (int kt = 0; kt < nk; ++kt) {
    __syncthreads();
    if (kt + 1 < nk) stage(cur ^ 1, (kt + 1) << 6);
#pragma unroll
    for (int kk = 0; kk < 2; ++kk) {
      u16x8 af[4], bfr[4];
#pragma unroll
      for (int m = 0; m < 4; ++m)
        af[m] = *(const u16x8*)&As[cur][wr * 64 + m * 16 + (lane & 15)][kk * 32 + (lane >> 4) * 8];
#pragma unroll
      for (int n = 0; n < 4; ++n)
        bfr[n] = *(const u16x8*)&Bs[cur][wc * 64 + n * 16 + (lane & 15)][kk * 32 + (lane >> 4) * 8];
#pragma unroll
      for (int m = 0; m < 4; ++m)
#pragma unroll
        for (int n = 0; n < 4; ++n)
          acc[m][n] = mfma16(af[m], bfr[n], acc[m][n]);
    }
    cur ^= 1;
  }
#pragma unroll
  for (int m = 0; m < 4; ++m) {
    int row = bm + wr * 64 + m * 16 + (lane >> 4) * 4;
#pragma unroll
    for (int n = 0; n < 4; ++n) {
      int col = bn + wc * 64 + n * 16 + (lane & 15);
#pragma unroll
      for (int j = 0; j < 4; ++j) stc(&C[(size_t)(row + j) * N + col], acc[m][n][j]);
    }
  }
}

// ---------- flash attention (causal): block = 128 q-rows x 1 head, 4 waves x 32 q-rows ----------
// K/V double-buffered in LDS, XOR-swizzled (pre-swizzled global src + swizzled reads).
__global__ __launch_bounds__(256, 3) void flash_attn(
    const unsigned short* __restrict__ Q,
    const unsigned short* __restrict__ Kt,
    const unsigned short* __restrict__ Vt,
    unsigned short* __restrict__ O) {
  __shared__ __attribute__((aligned(16))) unsigned short Ks[2][64][64];
  __shared__ __attribute__((aligned(16))) unsigned short Vs[2][64][64];  // [d][kv]
  __shared__ __attribute__((aligned(16))) unsigned short Ps[4][32][72];  // +8 pad: 2-way max
  const int tid = threadIdx.x;
  const int w = tid >> 6, lane = tid & 63;
  const int h = blockIdx.y;
  const int qt = (gridDim.x - 1) - blockIdx.x;  // heavy blocks first
  const int qb = qt * 128;
  const int r0 = (lane >> 4) * 4;

  // Q fragments: 2 x 16 rows per wave
  u16x8 qf[2][2];
#pragma unroll
  for (int f = 0; f < 2; ++f) {
    const unsigned short* qp =
        Q + ((size_t)h * S_LEN + qb + w * 32 + f * 16 + (lane & 15)) * 64 + (lane >> 4) * 8;
    qf[f][0] = *(const u16x8*)qp;
    qf[f][1] = *(const u16x8*)(qp + 32);
  }

  f32x4 acc[2][4] = {};
  float m_run[2][4], l_run[2][4];
#pragma unroll
  for (int f = 0; f < 2; ++f)
#pragma unroll
    for (int j = 0; j < 4; ++j) { m_run[f][j] = -1e30f; l_run[f][j] = 0.f; }

  // staging geometry: per (w,c) one 1 KiB chunk = 8 rows; source slot pre-swizzled
  const int rst = w * 16 + (lane >> 3);              // row within tile (+ c*8)
  const int sl = ((lane & 7) ^ (lane >> 3)) * 8;     // swizzled source slot (elems)
  const unsigned short* kb = Kt + (size_t)h * S_LEN * 64;
  const unsigned short* vb = Vt + (size_t)h * 64 * S_LEN;

  auto stage = [&](int buf, int kvt) {
#pragma unroll
    for (int c = 0; c < 2; ++c) {
      gload16(kb + ((size_t)kvt * 64 + rst + c * 8) * 64 + sl,
              (char*)&Ks[buf][0][0] + w * 2048 + c * 1024);
      gload16(vb + (size_t)(rst + c * 8) * S_LEN + (size_t)kvt * 64 + sl,
              (char*)&Vs[buf][0][0] + w * 2048 + c * 1024);
    }
  };

  const int nt = qt * 2 + 2;
  stage(0, 0);
  int cur = 0;
  for (int kvt = 0; kvt < nt; ++kvt) {
    __syncthreads();                       // buf[cur] staged; prior reads done
    if (kvt + 1 < nt) stage(cur ^ 1, kvt + 1);  // prefetch overlaps compute

    // ---- scores: 32 q-rows x 64 kv ----
    f32x4 sc[2][4] = {};
#pragma unroll
    for (int kk = 0; kk < 2; ++kk) {
#pragma unroll
      for (int nf = 0; nf < 4; ++nf) {
        const int rr = nf * 16 + (lane & 15);
        const int cb = kk * 64 + (lane >> 4) * 16;
        u16x8 bk = *(const u16x8*)((const char*)&Ks[cur][0][0] + rr * 128 + (cb ^ ((rr & 7) << 4)));
#pragma unroll
        for (int f = 0; f < 2; ++f) sc[f][nf] = mfma16(qf[f][kk], bk, sc[f][nf]);
      }
    }
    // ---- causal mask (only waves straddling the diagonal) ----
    if (kvt * 64 + 63 > qb + w * 32) {
#pragma unroll
      for (int f = 0; f < 2; ++f)
#pragma unroll
        for (int j = 0; j < 4; ++j) {
          const int qg = qb + w * 32 + f * 16 + r0 + j;
#pragma unroll
          for (int nf = 0; nf < 4; ++nf) {
            const int kg = kvt * 64 + nf * 16 + (lane & 15);
            if (kg > qg) sc[f][nf][j] = -1e30f;
          }
        }
    }
    // ---- online softmax ----
#pragma unroll
    for (int f = 0; f < 2; ++f)
#pragma unroll
      for (int j = 0; j < 4; ++j) {
        float mx = fmaxf(fmaxf(sc[f][0][j], sc[f][1][j]), fmaxf(sc[f][2][j], sc[f][3][j]));
#pragma unroll
        for (int msk = 1; msk < 16; msk <<= 1) mx = fmaxf(mx, __shfl_xor(mx, msk, 64));
        float mnew = fmaxf(m_run[f][j], mx);
        float alpha = __expf(m_run[f][j] - mnew);
        float rsum = 0.f;
#pragma unroll
        for (int nf = 0; nf < 4; ++nf) {
          float p = __expf(sc[f][nf][j] - mnew);
          rsum += p;
          Ps[w][f * 16 + r0 + j][nf * 16 + (lane & 15)] = f2bf(p);
        }
#pragma unroll
        for (int msk = 1; msk < 16; msk <<= 1) rsum += __shfl_xor(rsum, msk, 64);
        l_run[f][j] = l_run[f][j] * alpha + rsum;
        m_run[f][j] = mnew;
#pragma unroll
        for (int df = 0; df < 4; ++df) acc[f][df][j] *= alpha;
      }
    // wave-level fence: own Ps writes visible to own reads
    asm volatile("s_waitcnt lgkmcnt(0)" ::: "memory");
    // ---- PV ----
#pragma unroll
    for (int kk = 0; kk < 2; ++kk) {
      u16x8 pa[2];
#pragma unroll
      for (int f = 0; f < 2; ++f)
        pa[f] = *(const u16x8*)&Ps[w][f * 16 + (lane & 15)][kk * 32 + (lane >> 4) * 8];
#pragma unroll
      for (int df = 0; df < 4; ++df) {
        const int rr = df * 16 + (lane & 15);
        const int cb = kk * 64 + (lane >> 4) * 16;
        u16x8 bv = *(const u16x8*)((const char*)&Vs[cur][0][0] + rr * 128 + (cb ^ ((rr & 7) << 4)));
#pragma unroll
        for (int f = 0; f < 2; ++f) acc[f][df] = mfma16(pa[f], bv, acc[f][df]);
      }
    }
    cur ^= 1;
  }
  // ---- epilogue ----
#pragma unroll
  for (int f = 0; f < 2; ++f)
#pragma unroll
    for (int j = 0; j < 4; ++j) {
      const int qg = qb + w * 32 + f * 16 + r0 + j;
      const float inv = 1.0f / l_run[f][j];
#pragma unroll
      for (int df = 0; df < 4; ++df)
        O[(size_t)qg * HID + h * 64 + df * 16 + (lane & 15)] = f2bf(acc[f][df][j] * inv);
    }
}

extern "C" void kernel_launch(void* const* d_in, const int* in_sizes, int n_in,
                              void* d_out, int out_size, void* d_ws, size_t ws_size,
                              hipStream_t stream) {
  const float* x = (const float*)d_in[0];       // [4096][1024]
  const float* w_qkv = (const float*)d_in[1];   // [3072][1024]
  const float* w_out = (const float*)d_in[2];   // [1024][1024]
  float* out = (float*)d_out;                   // [4096][1024] f32
  char* ws = (char*)d_ws;

  unsigned short* xb    = (unsigned short*)(ws + 0);          // 8 MB
  unsigned short* wqkvb = (unsigned short*)(ws + 8388608);    // 6 MB
  unsigned short* woutb = (unsigned short*)(ws + 14680064);   // 2 MB
  unsigned short* qkvb  = (unsigned short*)(ws + 16777216);   // 24 MB [S][3072]
  unsigned short* Qb    = (unsigned short*)(ws + 41943040);   // 8 MB [H][S][64]
  unsigned short* Kb    = (unsigned short*)(ws + 50331648);   // 8 MB
  unsigned short* Vtb   = (unsigned short*)(ws + 58720256);   // 8 MB [H][64][S]
  unsigned short* attnb = (unsigned short*)(ws + 67108864);   // 8 MB [S][1024]
  float2* tab           = (float2*)(ws + 75497472);           // 1 MB

  k_cvt<<<dim3(4096), dim3(256), 0, stream>>>((const float4*)x, (ushort4*)xb, 1048576);
  k_cvt<<<dim3(3072), dim3(256), 0, stream>>>((const float4*)w_qkv, (ushort4*)wqkvb, 786432);
  k_cvt<<<dim3(1024), dim3(256), 0, stream>>>((const float4*)w_out, (ushort4*)woutb, 262144);
  k_rope_tab<<<dim3(512), dim3(256), 0, stream>>>(tab);

  gemm_bt<unsigned short><<<dim3(24, 32), dim3(256), 0, stream>>>(xb, wqkvb, qkvb, 4096, 3072, 1024);

  k_rope_split<<<dim3(4096), dim3(512), 0, stream>>>(qkvb, tab, Qb, Kb);
  k_vt<<<dim3(64, 16), dim3(256), 0, stream>>>(qkvb, Vtb);

  flash_attn<<<dim3(32, 16), dim3(256), 0, stream>>>(Qb, Kb, Vtb, attnb);

  gemm_bt<float><<<dim3(8, 32), dim3(256), 0, stream>>>(attnb, woutb, out, 4096, 1024, 1024);
}

// Round 3
// 231.275 us; speedup vs baseline: 1.7031x; 1.3011x over previous
//
#include <hip/hip_runtime.h>

#define S_LEN 4096
#define NHEAD 16
#define DHEAD 64
#define HID 1024

typedef float f32x4 __attribute__((ext_vector_type(4)));
typedef float f32x16 __attribute__((ext_vector_type(16)));
typedef unsigned short u16x8 __attribute__((ext_vector_type(8)));
typedef __bf16 bf16x8 __attribute__((ext_vector_type(8)));

__device__ __forceinline__ unsigned short f2bf(float f) {
  union { float f; unsigned u; } x; x.f = f;
  return (unsigned short)((x.u + 0x7FFFu + ((x.u >> 16) & 1u)) >> 16);
}
__device__ __forceinline__ float bf2f(unsigned short u) {
  union { unsigned u; float f; } x; x.u = ((unsigned)u) << 16;
  return x.f;
}
__device__ __forceinline__ f32x4 mfma16(u16x8 a, u16x8 b, f32x4 c) {
  return __builtin_amdgcn_mfma_f32_16x16x32_bf16(
      __builtin_bit_cast(bf16x8, a), __builtin_bit_cast(bf16x8, b), c, 0, 0, 0);
}
__device__ __forceinline__ f32x16 mfma32(u16x8 a, u16x8 b, f32x16 c) {
  return __builtin_amdgcn_mfma_f32_32x32x16_bf16(
      __builtin_bit_cast(bf16x8, a), __builtin_bit_cast(bf16x8, b), c, 0, 0, 0);
}
__device__ __forceinline__ void gload16(const void* g, void* l) {
  __builtin_amdgcn_global_load_lds(
      (const __attribute__((address_space(1))) void*)g,
      (__attribute__((address_space(3))) void*)l, 16, 0, 0);
}
// swap: a' = [a.lo | b.lo], b' = [a.hi | b.hi]
__device__ __forceinline__ void permswap(unsigned& a, unsigned& b) {
#if __has_builtin(__builtin_amdgcn_permlane32_swap)
  typedef unsigned u32x2 __attribute__((ext_vector_type(2)));
  u32x2 r = __builtin_amdgcn_permlane32_swap(a, b, false, false);
  a = r[0]; b = r[1];
#else
  asm volatile("v_permlane32_swap_b32 %0, %1" : "+v"(a), "+v"(b));
#endif
}
__device__ __forceinline__ unsigned cvtpk(float lo, float hi) {
  unsigned r;
  asm("v_cvt_pk_bf16_f32 %0, %1, %2" : "=v"(r) : "v"(lo), "v"(hi));
  return r;
}

// ---------- fused fp32 -> bf16 convert for all three tensors ----------
__global__ void k_cvt_all(const float4* __restrict__ x, const float4* __restrict__ wq,
                          const float4* __restrict__ wo, ushort4* __restrict__ xb,
                          ushort4* __restrict__ wqb, ushort4* __restrict__ wob) {
  int i = blockIdx.x * blockDim.x + threadIdx.x;  // 0..2097151
  const float4* src; ushort4* dst; int off;
  if (i < 1048576)      { src = x;  dst = xb;  off = i; }
  else if (i < 1835008) { src = wq; dst = wqb; off = i - 1048576; }
  else                  { src = wo; dst = wob; off = i - 1835008; }
  float4 v = src[off];
  ushort4 o;
  o.x = f2bf(v.x); o.y = f2bf(v.y); o.z = f2bf(v.z); o.w = f2bf(v.w);
  dst[off] = o;
}

// ---------- rope + split (table computed inline); K pre-scaled by 0.125*log2(e) ----------
__global__ void k_rope_split(const unsigned short* __restrict__ qkv,
                             unsigned short* __restrict__ Q,
                             unsigned short* __restrict__ Ko) {
  int s = blockIdx.x;
  int t = threadIdx.x;  // 512 threads
  int h = t >> 5, i = t & 31;
  float inv = __powf(10000.0f, -(float)i * (1.0f / 32.0f));
  float ang = (float)s * inv;
  float sn, cs;
  sincosf(ang, &sn, &cs);
  const unsigned short* row = qkv + (size_t)s * 3072;
  float q1 = bf2f(row[h * 64 + i]);
  float q2 = bf2f(row[h * 64 + i + 32]);
  float k1 = bf2f(row[1024 + h * 64 + i]);
  float k2 = bf2f(row[1024 + h * 64 + i + 32]);
  const float ksc = 0.125f * 1.44269504f;  // fold softmax scale + log2(e) into K
  size_t o = ((size_t)h * S_LEN + s) * 64 + i;
  Q[o]      = f2bf(q1 * cs - q2 * sn);
  Q[o + 32] = f2bf(q2 * cs + q1 * sn);
  Ko[o]      = f2bf((k1 * cs - k2 * sn) * ksc);
  Ko[o + 32] = f2bf((k2 * cs + k1 * sn) * ksc);
}

// ---------- V transpose: qkv v-part [S][h*64+d] -> Vt [H][64][S] ----------
__global__ void k_vt(const unsigned short* __restrict__ qkv,
                     unsigned short* __restrict__ Vt) {
  __shared__ unsigned short tile[64][65];
  int st = blockIdx.x, h = blockIdx.y;
  int t = threadIdx.x;  // 256
  int r = t >> 2, c0 = (t & 3) * 16;
  const unsigned short* src = qkv + (size_t)(st * 64 + r) * 3072 + 2048 + h * 64 + c0;
  u16x8 a = *(const u16x8*)src;
  u16x8 b = *(const u16x8*)(src + 8);
#pragma unroll
  for (int j = 0; j < 8; ++j) { tile[r][c0 + j] = a[j]; tile[r][c0 + 8 + j] = b[j]; }
  __syncthreads();
  unsigned short* dst = Vt + ((size_t)h * 64 + r) * S_LEN + st * 64 + c0;
  u16x8 o0, o1;
#pragma unroll
  for (int j = 0; j < 8; ++j) { o0[j] = tile[c0 + j][r]; o1[j] = tile[c0 + 8 + j][r]; }
  *(u16x8*)dst = o0;
  *(u16x8*)(dst + 8) = o1;
}

// ---------- GEMM: C[M][N] = A[M][K] * B[N][K]^T ----------
__device__ __forceinline__ void stc(float* p, float v) { *p = v; }
__device__ __forceinline__ void stc(unsigned short* p, float v) { *p = f2bf(v); }

template <typename OutT>
__global__ __launch_bounds__(256) void gemm_bt(
    const unsigned short* __restrict__ A, const unsigned short* __restrict__ B,
    OutT* __restrict__ C, int M, int N, int K) {
  __shared__ __attribute__((aligned(16))) unsigned short As[2][128][64];
  __shared__ __attribute__((aligned(16))) unsigned short Bs[2][128][64];
  const int tid = threadIdx.x;
  const int w = tid >> 6, lane = tid & 63;
  const int bm = blockIdx.y * 128, bn = blockIdx.x * 128;
  const int wr = w >> 1, wc = w & 1;
  const int l8 = lane >> 3;
  const int c8 = (lane & 7) * 8;
  f32x4 acc[4][4] = {};

  auto stage = [&](int buf, int k0) {
#pragma unroll
    for (int c = 0; c < 4; ++c) {
      int row = w * 32 + c * 8;
      gload16(A + (size_t)(bm + row + l8) * K + k0 + c8, &As[buf][row][0]);
      gload16(B + (size_t)(bn + row + l8) * K + k0 + c8, &Bs[buf][row][0]);
    }
  };

  const int nk = K >> 6;
  stage(0, 0);
  int cur = 0;
  for (int kt = 0; kt < nk; ++kt) {
    __syncthreads();
    if (kt + 1 < nk) stage(cur ^ 1, (kt + 1) << 6);
#pragma unroll
    for (int kk = 0; kk < 2; ++kk) {
      u16x8 af[4], bfr[4];
#pragma unroll
      for (int m = 0; m < 4; ++m)
        af[m] = *(const u16x8*)&As[cur][wr * 64 + m * 16 + (lane & 15)][kk * 32 + (lane >> 4) * 8];
#pragma unroll
      for (int n = 0; n < 4; ++n)
        bfr[n] = *(const u16x8*)&Bs[cur][wc * 64 + n * 16 + (lane & 15)][kk * 32 + (lane >> 4) * 8];
#pragma unroll
      for (int m = 0; m < 4; ++m)
#pragma unroll
        for (int n = 0; n < 4; ++n)
          acc[m][n] = mfma16(af[m], bfr[n], acc[m][n]);
    }
    cur ^= 1;
  }
#pragma unroll
  for (int m = 0; m < 4; ++m) {
    int row = bm + wr * 64 + m * 16 + (lane >> 4) * 4;
#pragma unroll
    for (int n = 0; n < 4; ++n) {
      int col = bn + wc * 64 + n * 16 + (lane & 15);
#pragma unroll
      for (int j = 0; j < 4; ++j) stc(&C[(size_t)(row + j) * N + col], acc[m][n][j]);
    }
  }
}

// ---------- flash attention (causal), swapped-operand in-register softmax ----------
// block = 128 q-rows x 1 head, 4 waves x 32 q-rows. 32x32x16 MFMA.
// sc = mfma(K, Q) -> D[kv][q]: lane owns q=lane&31, kv=(reg&3)+8*(reg>>2)+4*(lane>>5).
__global__ __launch_bounds__(256, 3) void flash_attn(
    const unsigned short* __restrict__ Q,
    const unsigned short* __restrict__ Kt,
    const unsigned short* __restrict__ Vt,
    unsigned short* __restrict__ O) {
  __shared__ __attribute__((aligned(16))) unsigned short Ks[2][64][64];
  __shared__ __attribute__((aligned(16))) unsigned short Vs[2][64][64];  // [d][kv]
  const int tid = threadIdx.x;
  const int w = tid >> 6, lane = tid & 63;
  const int q31 = lane & 31, hf = lane >> 5;
  const int h = blockIdx.y;
  const int qt = (gridDim.x - 1) - blockIdx.x;  // heavy blocks first
  const int qb = qt * 128;
  const int qg = qb + w * 32 + q31;  // this lane's q row

  // Q fragments (B-operand): lane holds Q[q31][c*16 + hf*8 + e]
  u16x8 qf[4];
  {
    const unsigned short* qp = Q + ((size_t)h * S_LEN + qg) * 64 + hf * 8;
#pragma unroll
    for (int c = 0; c < 4; ++c) qf[c] = *(const u16x8*)(qp + c * 16);
  }

  f32x16 accA = {}, accB = {};  // O^T[d][q], d-blocks 0-31 / 32-63
  float m_run = -1e30f, l_run = 0.f;

  // staging (pre-swizzled global source + linear LDS dest, read-side XOR)
  const int rst = w * 16 + (lane >> 3);
  const int sl = ((lane & 7) ^ (lane >> 3)) * 8;
  const unsigned short* kb = Kt + (size_t)h * S_LEN * 64;
  const unsigned short* vb = Vt + (size_t)h * 64 * S_LEN;

  auto stage = [&](int buf, int kvt) {
#pragma unroll
    for (int c = 0; c < 2; ++c) {
      gload16(kb + ((size_t)kvt * 64 + rst + c * 8) * 64 + sl,
              (char*)&Ks[buf][0][0] + w * 2048 + c * 1024);
      gload16(vb + (size_t)(rst + c * 8) * S_LEN + (size_t)kvt * 64 + sl,
              (char*)&Vs[buf][0][0] + w * 2048 + c * 1024);
    }
  };

  const int nt = qt * 2 + 2;
  stage(0, 0);
  int cur = 0;
  for (int kvt = 0; kvt < nt; ++kvt) {
    __syncthreads();
    if (kvt + 1 < nt) stage(cur ^ 1, kvt + 1);

    if (kvt * 64 <= qb + w * 32 + 31) {  // wave-uniform: skip fully-masked tiles
      const char* kbase = (const char*)&Ks[cur][0][0];
      const char* vbase = (const char*)&Vs[cur][0][0];
      // ---- QK^T (swapped): sc[kv][q] ----
      f32x16 sc0 = {}, sc1 = {};
      const int r1 = 32 + q31;
#pragma unroll
      for (int c = 0; c < 4; ++c) {
        const int cb = c * 32 + hf * 16;
        u16x8 k0 = *(const u16x8*)(kbase + q31 * 128 + (cb ^ ((q31 & 7) << 4)));
        u16x8 k1 = *(const u16x8*)(kbase + r1 * 128 + (cb ^ ((r1 & 7) << 4)));
        sc0 = mfma32(k0, qf[c], sc0);
        sc1 = mfma32(k1, qf[c], sc1);
      }
      // ---- causal mask ----
      if (kvt * 64 + 63 > qb + w * 32) {
#pragma unroll
        for (int r = 0; r < 16; ++r) {
          int kvl = kvt * 64 + (r & 3) + 8 * (r >> 2) + 4 * hf;
          if (kvl > qg) sc0[r] = -1e30f;
          if (kvl + 32 > qg) sc1[r] = -1e30f;
        }
      }
      // ---- row max (in-register tree + 1 permlane swap) ----
      float t[16];
#pragma unroll
      for (int r = 0; r < 16; ++r) t[r] = fmaxf(sc0[r], sc1[r]);
#pragma unroll
      for (int s = 8; s > 0; s >>= 1)
#pragma unroll
        for (int r = 0; r < 16; ++r) if (r < s) t[r] = fmaxf(t[r], t[r + s]);
      float pmax;
      {
        unsigned a = __float_as_uint(t[0]), b = a;
        permswap(a, b);
        pmax = fmaxf(__uint_as_float(a), __uint_as_float(b));
      }
      // ---- defer-max rescale (T13) ----
      if (!__all(pmax <= m_run + 11.0f)) {
        float mnew = fmaxf(m_run, pmax);
        float alpha = exp2f(m_run - mnew);
        m_run = mnew;
        l_run *= alpha;
#pragma unroll
        for (int r = 0; r < 16; ++r) { accA[r] *= alpha; accB[r] *= alpha; }
      }
      // ---- exp + row sum ----
      float p0[16], p1[16];
#pragma unroll
      for (int r = 0; r < 16; ++r) {
        p0[r] = exp2f(sc0[r] - m_run);
        p1[r] = exp2f(sc1[r] - m_run);
        t[r] = p0[r] + p1[r];
      }
#pragma unroll
      for (int s = 8; s > 0; s >>= 1)
#pragma unroll
        for (int r = 0; r < 16; ++r) if (r < s) t[r] += t[r + s];
      {
        unsigned a = __float_as_uint(t[0]), b = a;
        permswap(a, b);
        l_run += __uint_as_float(a) + __uint_as_float(b);
      }
      // ---- pack P to bf16 dwords ----
      unsigned dwb0[8], dwb1[8];
#pragma unroll
      for (int k = 0; k < 8; ++k) {
        dwb0[k] = cvtpk(p0[2 * k], p0[2 * k + 1]);
        dwb1[k] = cvtpk(p1[2 * k], p1[2 * k + 1]);
      }
      // ---- PV: O^T[d][q] += V^T[d][kv] * P[q][kv] ----
#pragma unroll
      for (int c = 0; c < 4; ++c) {
        unsigned x0 = (c >> 1) ? dwb1[4 * (c & 1) + 0] : dwb0[4 * (c & 1) + 0];
        unsigned y0 = (c >> 1) ? dwb1[4 * (c & 1) + 2] : dwb0[4 * (c & 1) + 2];
        unsigned x1 = (c >> 1) ? dwb1[4 * (c & 1) + 1] : dwb0[4 * (c & 1) + 1];
        unsigned y1 = (c >> 1) ? dwb1[4 * (c & 1) + 3] : dwb0[4 * (c & 1) + 3];
        permswap(x0, y0);
        permswap(x1, y1);
        union { u16x8 v; unsigned u[4]; } pf;
        pf.u[0] = x0; pf.u[1] = x1; pf.u[2] = y0; pf.u[3] = y1;
        const int cb = c * 32 + hf * 16;
        u16x8 v0 = *(const u16x8*)(vbase + q31 * 128 + (cb ^ ((q31 & 7) << 4)));
        u16x8 v1 = *(const u16x8*)(vbase + r1 * 128 + (cb ^ ((r1 & 7) << 4)));
        accA = mfma32(v0, pf.v, accA);
        accB = mfma32(v1, pf.v, accB);
      }
    }
    cur ^= 1;
  }

  // ---- epilogue: per-wave LDS transpose (reuse Ks) for coalesced O stores ----
  __syncthreads();  // all tile reads of Ks/Vs complete
  char* eb = (char*)&Ks[0][0][0] + w * 4096;  // [32 q][64 d] bf16, XOR-swizzled
  const float inv = 1.0f / l_run;
#pragma unroll
  for (int dblk = 0; dblk < 2; ++dblk) {
#pragma unroll
    for (int tt = 0; tt < 4; ++tt) {
      float a0, a1, a2, a3;
      if (dblk == 0) { a0 = accA[4 * tt]; a1 = accA[4 * tt + 1]; a2 = accA[4 * tt + 2]; a3 = accA[4 * tt + 3]; }
      else           { a0 = accB[4 * tt]; a1 = accB[4 * tt + 1]; a2 = accB[4 * tt + 2]; a3 = accB[4 * tt + 3]; }
      unsigned d0 = cvtpk(a0 * inv, a1 * inv);
      unsigned d1 = cvtpk(a2 * inv, a3 * inv);
      int dbase = dblk * 32 + 8 * tt + 4 * hf;
      int off = (q31 * 128 + dbase * 2) ^ ((q31 & 7) << 4);
      *(uint2*)(eb + off) = make_uint2(d0, d1);
    }
  }
  // same-wave RAW on LDS: compiler inserts lgkmcnt
#pragma unroll
  for (int pass = 0; pass < 4; ++pass) {
    int q = (lane >> 3) + pass * 8;
    int c8 = lane & 7;
    u16x8 vv = *(const u16x8*)(eb + ((q * 128 + c8 * 16) ^ ((q & 7) << 4)));
    *(u16x8*)(O + (size_t)(qb + w * 32 + q) * HID + h * 64 + c8 * 8) = vv;
  }
}

extern "C" void kernel_launch(void* const* d_in, const int* in_sizes, int n_in,
                              void* d_out, int out_size, void* d_ws, size_t ws_size,
                              hipStream_t stream) {
  const float* x = (const float*)d_in[0];       // [4096][1024]
  const float* w_qkv = (const float*)d_in[1];   // [3072][1024]
  const float* w_out = (const float*)d_in[2];   // [1024][1024]
  float* out = (float*)d_out;                   // [4096][1024] f32
  char* ws = (char*)d_ws;

  unsigned short* xb    = (unsigned short*)(ws + 0);          // 8 MB
  unsigned short* wqkvb = (unsigned short*)(ws + 8388608);    // 6 MB
  unsigned short* woutb = (unsigned short*)(ws + 14680064);   // 2 MB
  unsigned short* qkvb  = (unsigned short*)(ws + 16777216);   // 24 MB [S][3072]
  unsigned short* Qb    = (unsigned short*)(ws + 41943040);   // 8 MB [H][S][64]
  unsigned short* Kb    = (unsigned short*)(ws + 50331648);   // 8 MB
  unsigned short* Vtb   = (unsigned short*)(ws + 58720256);   // 8 MB [H][64][S]
  unsigned short* attnb = (unsigned short*)(ws + 67108864);   // 8 MB [S][1024]

  k_cvt_all<<<dim3(8192), dim3(256), 0, stream>>>(
      (const float4*)x, (const float4*)w_qkv, (const float4*)w_out,
      (ushort4*)xb, (ushort4*)wqkvb, (ushort4*)woutb);

  gemm_bt<unsigned short><<<dim3(24, 32), dim3(256), 0, stream>>>(xb, wqkvb, qkvb, 4096, 3072, 1024);

  k_rope_split<<<dim3(4096), dim3(512), 0, stream>>>(qkvb, Qb, Kb);
  k_vt<<<dim3(64, 16), dim3(256), 0, stream>>>(qkvb, Vtb);

  flash_attn<<<dim3(32, 16), dim3(256), 0, stream>>>(Qb, Kb, Vtb, attnb);

  gemm_bt<float><<<dim3(8, 32), dim3(256), 0, stream>>>(attnb, woutb, out, 4096, 1024, 1024);
}

// Round 4
// 203.266 us; speedup vs baseline: 1.9378x; 1.1378x over previous
//
#include <hip/hip_runtime.h>

#define S_LEN 4096
#define NHEAD 16
#define DHEAD 64
#define HID 1024

typedef float f32x4 __attribute__((ext_vector_type(4)));
typedef float f32x16 __attribute__((ext_vector_type(16)));
typedef unsigned short u16x8 __attribute__((ext_vector_type(8)));
typedef __bf16 bf16x8 __attribute__((ext_vector_type(8)));

__device__ __forceinline__ unsigned short f2bf(float f) {
  union { float f; unsigned u; } x; x.f = f;
  return (unsigned short)((x.u + 0x7FFFu + ((x.u >> 16) & 1u)) >> 16);
}
__device__ __forceinline__ float bf2f(unsigned short u) {
  union { unsigned u; float f; } x; x.u = ((unsigned)u) << 16;
  return x.f;
}
__device__ __forceinline__ f32x4 mfma16(u16x8 a, u16x8 b, f32x4 c) {
  return __builtin_amdgcn_mfma_f32_16x16x32_bf16(
      __builtin_bit_cast(bf16x8, a), __builtin_bit_cast(bf16x8, b), c, 0, 0, 0);
}
__device__ __forceinline__ f32x16 mfma32(u16x8 a, u16x8 b, f32x16 c) {
  return __builtin_amdgcn_mfma_f32_32x32x16_bf16(
      __builtin_bit_cast(bf16x8, a), __builtin_bit_cast(bf16x8, b), c, 0, 0, 0);
}
__device__ __forceinline__ void gload16(const void* g, void* l) {
  __builtin_amdgcn_global_load_lds(
      (const __attribute__((address_space(1))) void*)g,
      (__attribute__((address_space(3))) void*)l, 16, 0, 0);
}
// swap: a' = [a.lo | b.lo], b' = [a.hi | b.hi]
__device__ __forceinline__ void permswap(unsigned& a, unsigned& b) {
#if __has_builtin(__builtin_amdgcn_permlane32_swap)
  typedef unsigned u32x2 __attribute__((ext_vector_type(2)));
  u32x2 r = __builtin_amdgcn_permlane32_swap(a, b, false, false);
  a = r[0]; b = r[1];
#else
  asm volatile("v_permlane32_swap_b32 %0, %1" : "+v"(a), "+v"(b));
#endif
}
__device__ __forceinline__ unsigned cvtpk(float lo, float hi) {
  unsigned r;
  asm("v_cvt_pk_bf16_f32 %0, %1, %2" : "=v"(r) : "v"(lo), "v"(hi));
  return r;
}

// ---------- fused fp32 -> bf16 convert for all three tensors ----------
__global__ void k_cvt_all(const float4* __restrict__ x, const float4* __restrict__ wq,
                          const float4* __restrict__ wo, ushort4* __restrict__ xb,
                          ushort4* __restrict__ wqb, ushort4* __restrict__ wob) {
  int i = blockIdx.x * blockDim.x + threadIdx.x;  // 0..2097151
  const float4* src; ushort4* dst; int off;
  if (i < 1048576)      { src = x;  dst = xb;  off = i; }
  else if (i < 1835008) { src = wq; dst = wqb; off = i - 1048576; }
  else                  { src = wo; dst = wob; off = i - 1835008; }
  float4 v = src[off];
  ushort4 o;
  o.x = f2bf(v.x); o.y = f2bf(v.y); o.z = f2bf(v.z); o.w = f2bf(v.w);
  dst[off] = o;
}

// ---------- rope + split (table computed inline); K pre-scaled by 0.125*log2(e) ----------
__global__ void k_rope_split(const unsigned short* __restrict__ qkv,
                             unsigned short* __restrict__ Q,
                             unsigned short* __restrict__ Ko) {
  int s = blockIdx.x;
  int t = threadIdx.x;  // 512 threads
  int h = t >> 5, i = t & 31;
  float inv = __powf(10000.0f, -(float)i * (1.0f / 32.0f));
  float ang = (float)s * inv;
  float sn, cs;
  sincosf(ang, &sn, &cs);
  const unsigned short* row = qkv + (size_t)s * 3072;
  float q1 = bf2f(row[h * 64 + i]);
  float q2 = bf2f(row[h * 64 + i + 32]);
  float k1 = bf2f(row[1024 + h * 64 + i]);
  float k2 = bf2f(row[1024 + h * 64 + i + 32]);
  const float ksc = 0.125f * 1.44269504f;  // fold softmax scale + log2(e) into K
  size_t o = ((size_t)h * S_LEN + s) * 64 + i;
  Q[o]      = f2bf(q1 * cs - q2 * sn);
  Q[o + 32] = f2bf(q2 * cs + q1 * sn);
  Ko[o]      = f2bf((k1 * cs - k2 * sn) * ksc);
  Ko[o + 32] = f2bf((k2 * cs + k1 * sn) * ksc);
}

// ---------- V transpose: qkv v-part [S][h*64+d] -> Vt [H][64][S] ----------
__global__ void k_vt(const unsigned short* __restrict__ qkv,
                     unsigned short* __restrict__ Vt) {
  __shared__ unsigned short tile[64][65];
  int st = blockIdx.x, h = blockIdx.y;
  int t = threadIdx.x;  // 256
  int r = t >> 2, c0 = (t & 3) * 16;
  const unsigned short* src = qkv + (size_t)(st * 64 + r) * 3072 + 2048 + h * 64 + c0;
  u16x8 a = *(const u16x8*)src;
  u16x8 b = *(const u16x8*)(src + 8);
#pragma unroll
  for (int j = 0; j < 8; ++j) { tile[r][c0 + j] = a[j]; tile[r][c0 + 8 + j] = b[j]; }
  __syncthreads();
  unsigned short* dst = Vt + ((size_t)h * 64 + r) * S_LEN + st * 64 + c0;
  u16x8 o0, o1;
#pragma unroll
  for (int j = 0; j < 8; ++j) { o0[j] = tile[c0 + j][r]; o1[j] = tile[c0 + 8 + j][r]; }
  *(u16x8*)dst = o0;
  *(u16x8*)(dst + 8) = o1;
}

// ---------- GEMM: C[M][N] = A[M][K] * B[N][K]^T ----------
__device__ __forceinline__ void stc(float* p, float v) { *p = v; }
__device__ __forceinline__ void stc(unsigned short* p, float v) { *p = f2bf(v); }

template <typename OutT>
__global__ __launch_bounds__(256) void gemm_bt(
    const unsigned short* __restrict__ A, const unsigned short* __restrict__ B,
    OutT* __restrict__ C, int M, int N, int K) {
  __shared__ __attribute__((aligned(16))) unsigned short As[2][128][64];
  __shared__ __attribute__((aligned(16))) unsigned short Bs[2][128][64];
  const int tid = threadIdx.x;
  const int w = tid >> 6, lane = tid & 63;
  const int bm = blockIdx.y * 128, bn = blockIdx.x * 128;
  const int wr = w >> 1, wc = w & 1;
  const int l8 = lane >> 3;
  const int c8 = (lane & 7) * 8;
  f32x4 acc[4][4] = {};

  auto stage = [&](int buf, int k0) {
#pragma unroll
    for (int c = 0; c < 4; ++c) {
      int row = w * 32 + c * 8;
      gload16(A + (size_t)(bm + row + l8) * K + k0 + c8, &As[buf][row][0]);
      gload16(B + (size_t)(bn + row + l8) * K + k0 + c8, &Bs[buf][row][0]);
    }
  };

  const int nk = K >> 6;
  stage(0, 0);
  int cur = 0;
  for (int kt = 0; kt < nk; ++kt) {
    __syncthreads();
    if (kt + 1 < nk) stage(cur ^ 1, (kt + 1) << 6);
#pragma unroll
    for (int kk = 0; kk < 2; ++kk) {
      u16x8 af[4], bfr[4];
#pragma unroll
      for (int m = 0; m < 4; ++m)
        af[m] = *(const u16x8*)&As[cur][wr * 64 + m * 16 + (lane & 15)][kk * 32 + (lane >> 4) * 8];
#pragma unroll
      for (int n = 0; n < 4; ++n)
        bfr[n] = *(const u16x8*)&Bs[cur][wc * 64 + n * 16 + (lane & 15)][kk * 32 + (lane >> 4) * 8];
#pragma unroll
      for (int m = 0; m < 4; ++m)
#pragma unroll
        for (int n = 0; n < 4; ++n)
          acc[m][n] = mfma16(af[m], bfr[n], acc[m][n]);
    }
    cur ^= 1;
  }
#pragma unroll
  for (int m = 0; m < 4; ++m) {
    int row = bm + wr * 64 + m * 16 + (lane >> 4) * 4;
#pragma unroll
    for (int n = 0; n < 4; ++n) {
      int col = bn + wc * 64 + n * 16 + (lane & 15);
#pragma unroll
      for (int j = 0; j < 4; ++j) stc(&C[(size_t)(row + j) * N + col], acc[m][n][j]);
    }
  }
}

// ---------- flash attention (causal), swapped-operand in-register softmax ----------
// block = 128 q-rows x 1 head, 4 waves x 32 q-rows. 32x32x16 MFMA.
// qt complement-swizzled for CU/XCD load balance; K/V triple-buffered with
// counted vmcnt + raw s_barrier (loads stay in flight across barriers).
__global__ __launch_bounds__(256, 3) void flash_attn(
    const unsigned short* __restrict__ Q,
    const unsigned short* __restrict__ Kt,
    const unsigned short* __restrict__ Vt,
    unsigned short* __restrict__ O) {
  __shared__ __attribute__((aligned(16))) unsigned short Ks[3][64][64];
  __shared__ __attribute__((aligned(16))) unsigned short Vs[3][64][64];  // [d][kv]
  const int tid = threadIdx.x;
  const int w = tid >> 6, lane = tid & 63;
  const int q31 = lane & 31, hf = lane >> 5;
  const int h = blockIdx.y;
  // complement swizzle: co-resident pairs (y, y+8) get qt sums = 31 (CU balance);
  // every x-column sums to equal work (XCD balance under id%8 round-robin).
  const int qt = (blockIdx.y & 8) ? blockIdx.x : (31 - blockIdx.x);
  const int qb = qt * 128;
  const int qg = qb + w * 32 + q31;  // this lane's q row

  // Q fragments (B-operand): lane holds Q[q31][c*16 + hf*8 + e]
  u16x8 qf[4];
  {
    const unsigned short* qp = Q + ((size_t)h * S_LEN + qg) * 64 + hf * 8;
#pragma unroll
    for (int c = 0; c < 4; ++c) qf[c] = *(const u16x8*)(qp + c * 16);
  }

  f32x16 accA = {}, accB = {};  // O^T[d][q], d-blocks 0-31 / 32-63
  float m_run = -1e30f, l_run = 0.f;

  // staging (pre-swizzled global source + linear LDS dest, read-side XOR)
  const int rst = w * 16 + (lane >> 3);
  const int sl = ((lane & 7) ^ (lane >> 3)) * 8;
  const unsigned short* kb = Kt + (size_t)h * S_LEN * 64;
  const unsigned short* vb = Vt + (size_t)h * 64 * S_LEN;

  auto stage = [&](int buf, int kvt) {
#pragma unroll
    for (int c = 0; c < 2; ++c) {
      gload16(kb + ((size_t)kvt * 64 + rst + c * 8) * 64 + sl,
              (char*)&Ks[buf][0][0] + w * 2048 + c * 1024);
      gload16(vb + (size_t)(rst + c * 8) * S_LEN + (size_t)kvt * 64 + sl,
              (char*)&Vs[buf][0][0] + w * 2048 + c * 1024);
    }
  };

  const int nt = qt * 2 + 2;
  stage(0, 0);
  stage(1, 1);
  int cur = 0;
  for (int kvt = 0; kvt < nt; ++kvt) {
    // wait ONLY the oldest tile's 4 loads (tile kvt); tiles kvt+1 stay in flight
    asm volatile("s_waitcnt vmcnt(4)" ::: "memory");
    __builtin_amdgcn_sched_barrier(0);
    __builtin_amdgcn_s_barrier();
    __builtin_amdgcn_sched_barrier(0);
    // after barrier all waves are done reading buf[(kvt+2)%3] (== tile kvt-1)
    {
      const int sbuf = (cur + 2 >= 3) ? cur - 1 : cur + 2;
      const int stile = (kvt + 2 < nt) ? kvt + 2 : nt - 1;  // clamp: redundant, keeps vmcnt constant
      stage(sbuf, stile);
    }

    if (kvt * 64 <= qb + w * 32 + 31) {  // wave-uniform: skip fully-masked tiles
      const char* kbase = (const char*)&Ks[cur][0][0];
      const char* vbase = (const char*)&Vs[cur][0][0];
      // ---- QK^T (swapped): sc[kv][q] ----
      f32x16 sc0 = {}, sc1 = {};
      const int r1 = 32 + q31;
      __builtin_amdgcn_s_setprio(1);
#pragma unroll
      for (int c = 0; c < 4; ++c) {
        const int cb = c * 32 + hf * 16;
        u16x8 k0 = *(const u16x8*)(kbase + q31 * 128 + (cb ^ ((q31 & 7) << 4)));
        u16x8 k1 = *(const u16x8*)(kbase + r1 * 128 + (cb ^ ((r1 & 7) << 4)));
        sc0 = mfma32(k0, qf[c], sc0);
        sc1 = mfma32(k1, qf[c], sc1);
      }
      __builtin_amdgcn_s_setprio(0);
      // ---- causal mask ----
      if (kvt * 64 + 63 > qb + w * 32) {
#pragma unroll
        for (int r = 0; r < 16; ++r) {
          int kvl = kvt * 64 + (r & 3) + 8 * (r >> 2) + 4 * hf;
          if (kvl > qg) sc0[r] = -1e30f;
          if (kvl + 32 > qg) sc1[r] = -1e30f;
        }
      }
      // ---- row max (in-register tree + 1 permlane swap) ----
      float t[16];
#pragma unroll
      for (int r = 0; r < 16; ++r) t[r] = fmaxf(sc0[r], sc1[r]);
#pragma unroll
      for (int s = 8; s > 0; s >>= 1)
#pragma unroll
        for (int r = 0; r < 16; ++r) if (r < s) t[r] = fmaxf(t[r], t[r + s]);
      float pmax;
      {
        unsigned a = __float_as_uint(t[0]), b = a;
        permswap(a, b);
        pmax = fmaxf(__uint_as_float(a), __uint_as_float(b));
      }
      // ---- defer-max rescale (T13) ----
      if (!__all(pmax <= m_run + 11.0f)) {
        float mnew = fmaxf(m_run, pmax);
        float alpha = exp2f(m_run - mnew);
        m_run = mnew;
        l_run *= alpha;
#pragma unroll
        for (int r = 0; r < 16; ++r) { accA[r] *= alpha; accB[r] *= alpha; }
      }
      // ---- exp + row sum ----
      float p0[16], p1[16];
#pragma unroll
      for (int r = 0; r < 16; ++r) {
        p0[r] = exp2f(sc0[r] - m_run);
        p1[r] = exp2f(sc1[r] - m_run);
        t[r] = p0[r] + p1[r];
      }
#pragma unroll
      for (int s = 8; s > 0; s >>= 1)
#pragma unroll
        for (int r = 0; r < 16; ++r) if (r < s) t[r] += t[r + s];
      {
        unsigned a = __float_as_uint(t[0]), b = a;
        permswap(a, b);
        l_run += __uint_as_float(a) + __uint_as_float(b);
      }
      // ---- pack P to bf16 dwords ----
      unsigned dwb0[8], dwb1[8];
#pragma unroll
      for (int k = 0; k < 8; ++k) {
        dwb0[k] = cvtpk(p0[2 * k], p0[2 * k + 1]);
        dwb1[k] = cvtpk(p1[2 * k], p1[2 * k + 1]);
      }
      // ---- PV: O^T[d][q] += V^T[d][kv] * P[q][kv] ----
      __builtin_amdgcn_s_setprio(1);
#pragma unroll
      for (int c = 0; c < 4; ++c) {
        unsigned x0 = (c >> 1) ? dwb1[4 * (c & 1) + 0] : dwb0[4 * (c & 1) + 0];
        unsigned y0 = (c >> 1) ? dwb1[4 * (c & 1) + 2] : dwb0[4 * (c & 1) + 2];
        unsigned x1 = (c >> 1) ? dwb1[4 * (c & 1) + 1] : dwb0[4 * (c & 1) + 1];
        unsigned y1 = (c >> 1) ? dwb1[4 * (c & 1) + 3] : dwb0[4 * (c & 1) + 3];
        permswap(x0, y0);
        permswap(x1, y1);
        union { u16x8 v; unsigned u[4]; } pf;
        pf.u[0] = x0; pf.u[1] = x1; pf.u[2] = y0; pf.u[3] = y1;
        const int cb = c * 32 + hf * 16;
        u16x8 v0 = *(const u16x8*)(vbase + q31 * 128 + (cb ^ ((q31 & 7) << 4)));
        u16x8 v1 = *(const u16x8*)(vbase + r1 * 128 + (cb ^ ((r1 & 7) << 4)));
        accA = mfma32(v0, pf.v, accA);
        accB = mfma32(v1, pf.v, accB);
      }
      __builtin_amdgcn_s_setprio(0);
    }
    cur = (cur + 1 == 3) ? 0 : cur + 1;
  }

  // ---- epilogue: per-wave LDS transpose (reuse Ks) for coalesced O stores ----
  __syncthreads();  // drains all outstanding loads; all tile reads complete
  char* eb = (char*)&Ks[0][0][0] + w * 4096;  // [32 q][64 d] bf16, XOR-swizzled
  const float inv = 1.0f / l_run;
#pragma unroll
  for (int dblk = 0; dblk < 2; ++dblk) {
#pragma unroll
    for (int tt = 0; tt < 4; ++tt) {
      float a0, a1, a2, a3;
      if (dblk == 0) { a0 = accA[4 * tt]; a1 = accA[4 * tt + 1]; a2 = accA[4 * tt + 2]; a3 = accA[4 * tt + 3]; }
      else           { a0 = accB[4 * tt]; a1 = accB[4 * tt + 1]; a2 = accB[4 * tt + 2]; a3 = accB[4 * tt + 3]; }
      unsigned d0 = cvtpk(a0 * inv, a1 * inv);
      unsigned d1 = cvtpk(a2 * inv, a3 * inv);
      int dbase = dblk * 32 + 8 * tt + 4 * hf;
      int off = (q31 * 128 + dbase * 2) ^ ((q31 & 7) << 4);
      *(uint2*)(eb + off) = make_uint2(d0, d1);
    }
  }
  // same-wave RAW on LDS: compiler inserts lgkmcnt
#pragma unroll
  for (int pass = 0; pass < 4; ++pass) {
    int q = (lane >> 3) + pass * 8;
    int c8 = lane & 7;
    u16x8 vv = *(const u16x8*)(eb + ((q * 128 + c8 * 16) ^ ((q & 7) << 4)));
    *(u16x8*)(O + (size_t)(qb + w * 32 + q) * HID + h * 64 + c8 * 8) = vv;
  }
}

extern "C" void kernel_launch(void* const* d_in, const int* in_sizes, int n_in,
                              void* d_out, int out_size, void* d_ws, size_t ws_size,
                              hipStream_t stream) {
  const float* x = (const float*)d_in[0];       // [4096][1024]
  const float* w_qkv = (const float*)d_in[1];   // [3072][1024]
  const float* w_out = (const float*)d_in[2];   // [1024][1024]
  float* out = (float*)d_out;                   // [4096][1024] f32
  char* ws = (char*)d_ws;

  unsigned short* xb    = (unsigned short*)(ws + 0);          // 8 MB
  unsigned short* wqkvb = (unsigned short*)(ws + 8388608);    // 6 MB
  unsigned short* woutb = (unsigned short*)(ws + 14680064);   // 2 MB
  unsigned short* qkvb  = (unsigned short*)(ws + 16777216);   // 24 MB [S][3072]
  unsigned short* Qb    = (unsigned short*)(ws + 41943040);   // 8 MB [H][S][64]
  unsigned short* Kb    = (unsigned short*)(ws + 50331648);   // 8 MB
  unsigned short* Vtb   = (unsigned short*)(ws + 58720256);   // 8 MB [H][64][S]
  unsigned short* attnb = (unsigned short*)(ws + 67108864);   // 8 MB [S][1024]

  k_cvt_all<<<dim3(8192), dim3(256), 0, stream>>>(
      (const float4*)x, (const float4*)w_qkv, (const float4*)w_out,
      (ushort4*)xb, (ushort4*)wqkvb, (ushort4*)woutb);

  gemm_bt<unsigned short><<<dim3(24, 32), dim3(256), 0, stream>>>(xb, wqkvb, qkvb, 4096, 3072, 1024);

  k_rope_split<<<dim3(4096), dim3(512), 0, stream>>>(qkvb, Qb, Kb);
  k_vt<<<dim3(64, 16), dim3(256), 0, stream>>>(qkvb, Vtb);

  flash_attn<<<dim3(32, 16), dim3(256), 0, stream>>>(Qb, Kb, Vtb, attnb);

  gemm_bt<float><<<dim3(8, 32), dim3(256), 0, stream>>>(attnb, woutb, out, 4096, 1024, 1024);
}